// Round 9
// baseline (845.852 us; speedup 1.0000x reference)
//
#include <hip/hip_runtime.h>
#include <hip/hip_cooperative_groups.h>
#include <math.h>

namespace cg = cooperative_groups;

#define NN 50000
#define NE 800000
#define NB 196        // dst buckets of 256 nodes
#define PBH 8192      // halfs per packed 64x64 W block: 2ks*2hl*4ct*64lane*8

typedef float v4f __attribute__((ext_vector_type(4)));
typedef float v2f __attribute__((ext_vector_type(2)));
typedef _Float16 v8h __attribute__((ext_vector_type(8)));

// ---------------- fp8 e4m3fn helpers: HW builtins w/ fallback ----------------
__device__ __forceinline__ unsigned char enc8(float v) {
#if __has_builtin(__builtin_amdgcn_cvt_pk_fp8_f32)
  return (unsigned char)(__builtin_amdgcn_cvt_pk_fp8_f32(v, v, 0, false) & 0xFF);
#else
  unsigned u = __float_as_uint(v);
  unsigned s = (u >> 24) & 0x80u;
  unsigned au = u & 0x7fffffffu;
  float a = __uint_as_float(au);
  if (au < 0x3C800000u) {
    int m = (int)(a * 512.0f + 0.5f);
    if (m >= 8) return (unsigned char)(s | 8u);
    return (unsigned char)(s | (unsigned)m);
  }
  unsigned r = au + 0x7FFFFu + ((au >> 20) & 1u);
  unsigned e = (r >> 23) - 120u;
  unsigned man = (r >> 20) & 7u;
  if (e > 15u) { e = 15u; man = 6u; }
  return (unsigned char)(s | (e << 3) | man);
#endif
}

#if __has_builtin(__builtin_amdgcn_cvt_pk_f32_fp8)
#define DEC8_HW 1
#else
__device__ __forceinline__ float dec8_1(unsigned b) {
  unsigned s = (b & 0x80u) << 24;
  unsigned em = b & 0x7fu;
  float v;
  if (em >= 8u) v = __uint_as_float((((em >> 3) + 120u) << 23) | ((em & 7u) << 20));
  else v = (float)em * 0.001953125f;
  return __uint_as_float(__float_as_uint(v) | s);
}
#endif

__device__ __forceinline__ void dec8x8(uint2 u, float* f) {
#ifdef DEC8_HW
  v2f p0 = __builtin_amdgcn_cvt_pk_f32_fp8((int)u.x, false);
  v2f p1 = __builtin_amdgcn_cvt_pk_f32_fp8((int)u.x, true);
  v2f p2 = __builtin_amdgcn_cvt_pk_f32_fp8((int)u.y, false);
  v2f p3 = __builtin_amdgcn_cvt_pk_f32_fp8((int)u.y, true);
  f[0] = p0.x; f[1] = p0.y; f[2] = p1.x; f[3] = p1.y;
  f[4] = p2.x; f[5] = p2.y; f[6] = p3.x; f[7] = p3.y;
#else
#pragma unroll
  for (int i = 0; i < 4; ++i) f[i] = dec8_1((u.x >> (8 * i)) & 0xFF);
#pragma unroll
  for (int i = 0; i < 4; ++i) f[4 + i] = dec8_1((u.y >> (8 * i)) & 0xFF);
#endif
}
__device__ __forceinline__ void dec8x16(uint4 u, float* f) {
  dec8x8(make_uint2(u.x, u.y), f);
  dec8x8(make_uint2(u.z, u.w), f + 8);
}

// =================== COOPERATIVE KERNEL 1: graph build + wpack ================
struct GArgs {
  const int* esrc; const int* edst;
  int* gbcnt; int* boff; int* gcur; int* offs; float* invd; int* csr;
  unsigned* ebuf; float* sv;
  const float* w[15]; int gidx[15]; const float* skip; _Float16* wpk;
};

__global__ __launch_bounds__(256) void k_graph(GArgs A) {
  cg::grid_group grid = cg::this_grid();
  __shared__ int s0[NB];
  __shared__ int s1[256];
  __shared__ int s2[256];
  __shared__ float sw[4096];
  const int b = blockIdx.x, t = threadIdx.x;

  // phase 0: zero counters + sv
  if (t == 0) A.gbcnt[b] = 0;
  if (b == 0) A.sv[t] = 0.f;
  grid.sync();

  // phase A: bucket histogram
  for (int i = t; i < NB; i += 256) s0[i] = 0;
  __syncthreads();
  const int eb = b * 4096;
#pragma unroll
  for (int i = 0; i < 16; ++i) {
    int e = eb + i * 256 + t;
    if (e < NE) atomicAdd(&s0[A.edst[e] >> 8], 1);
  }
  __syncthreads();
  for (int i = t; i < NB; i += 256)
    if (s0[i]) atomicAdd(&A.gbcnt[i], s0[i]);
  grid.sync();

  // phase B: scan (block 0)
  if (b == 0) {
    int v = (t < NB) ? A.gbcnt[t] : 0;
    s1[t] = v;
    __syncthreads();
    for (int o = 1; o < 256; o <<= 1) {
      int u = (t >= o) ? s1[t - o] : 0;
      __syncthreads();
      s1[t] += u;
      __syncthreads();
    }
    if (t < NB) { int x = s1[t] - v; A.boff[t] = x; A.gcur[t] = x; }
    if (t == NB - 1) A.boff[NB] = s1[t];
    if (t == 0) A.offs[NN] = NE;
  }
  grid.sync();

  // phase C: scatter packed edges
  for (int i = t; i < NB; i += 256) s0[i] = 0;
  __syncthreads();
  unsigned pk[16]; int bk[16], lp[16];
#pragma unroll
  for (int i = 0; i < 16; ++i) {
    int e = eb + i * 256 + t;
    if (e < NE) {
      int d = A.edst[e];
      int bb = d >> 8;
      pk[i] = ((unsigned)A.esrc[e] << 8) | (unsigned)(d & 255);
      bk[i] = bb;
      lp[i] = atomicAdd(&s0[bb], 1);
    }
  }
  __syncthreads();
  for (int i = t; i < NB; i += 256)
    s1[i] = s0[i] ? atomicAdd(&A.gcur[i], s0[i]) : 0;
  __syncthreads();
#pragma unroll
  for (int i = 0; i < 16; ++i) {
    int e = eb + i * 256 + t;
    if (e < NE) A.ebuf[s1[bk[i]] + lp[i]] = pk[i];
  }
  grid.sync();

  // phase D: per-bucket degree + csr
  {
    int node0 = b << 8;
    int es = A.boff[b], ee = A.boff[b + 1];
    s2[t] = 0;
    __syncthreads();
    for (int e = es + t; e < ee; e += 256) atomicAdd(&s2[A.ebuf[e] & 255], 1);
    __syncthreads();
    int v = s2[t];
    s1[t] = v;
    __syncthreads();
    for (int o = 1; o < 256; o <<= 1) {
      int u = (t >= o) ? s1[t - o] : 0;
      __syncthreads();
      s1[t] += u;
      __syncthreads();
    }
    int excl = s1[t] - v;
    int node = node0 + t;
    if (node < NN) {
      A.offs[node] = es + excl;
      A.invd[node] = 1.0f / fmaxf((float)v, 1.0f);
    }
    __syncthreads();
    s1[t] = es + excl;
    __syncthreads();
    for (int e = es + t; e < ee; e += 256) {
      unsigned pk2 = A.ebuf[e];
      int p = atomicAdd(&s1[pk2 & 255], 1);
      A.csr[p] = (int)(pk2 >> 8);
    }
  }

  // phase E: weight pre-pack (blocks 0..14), independent of graph
  if (b < 15) {
    const float* w = A.w[b];
#pragma unroll
    for (int i = 0; i < 4; ++i)
      *(float4*)&sw[i * 1024 + t * 4] = *(const float4*)(w + i * 1024 + t * 4);
    float gs = 1.f;
    if (A.gidx[b] >= 0) gs = 1.f / (1.f + __expf(-A.skip[A.gidx[b]]));
    __syncthreads();
#pragma unroll
    for (int i = 0; i < 4; ++i) {
      int u = t * 4 + i;   // u = ks*512 + hl*256 + ct*64 + lane
      int lane = u & 63, ct = (u >> 6) & 3, hl = (u >> 8) & 1, ks = (u >> 9) & 1;
      v8h val;
#pragma unroll
      for (int j = 0; j < 8; ++j) {
        int k = ks * 32 + ((lane >> 4) & 3) * 8 + j;
        int n = ct * 16 + (lane & 15);
        float f = sw[k * 64 + n] * gs;
        _Float16 h = (_Float16)f;
        val[j] = hl ? (_Float16)(f - (float)h) : h;
      }
      *(v8h*)(A.wpk + (size_t)b * PBH + (size_t)u * 8) = val;
    }
  }
}

// =================== COOPERATIVE KERNEL 2: full compute chain =================
struct CArgs {
  const float* nf; const _Float16* wpk;
  const float* preb1; const float* preb2;
  const float* bl0; const float* bl1; const float* bl2;
  const int* offs; const int* csr; const float* invd;
  _Float16 *x, *h0, *h1, *m0, *m1;
  unsigned char *f8a, *f8b;
  float* sv;
  const float *pw1, *pb1, *pw2, *pb2, *pw3, *pb3, *pw4, *pb4;
  float* outp;
  int n;
};

// gather/mean: 4 thr/node over 256-thread half-block (measured round-4 body)
__device__ __forceinline__ void gather_tile(int t, int n0,
    const unsigned char* __restrict__ fb, const int* __restrict__ offs,
    const int* __restrict__ csr, const float* __restrict__ invd,
    _Float16* atile, _Float16* mout, int n) {
  const int nd = t >> 2, q = t & 3;
  const int node = n0 + nd;
  float a[16];
#pragma unroll
  for (int i = 0; i < 16; ++i) a[i] = 0.f;
  float dinv = 0.f;
  if (node < n) {
    int s = offs[node], e = offs[node + 1];
    dinv = invd[node];
    int p = s;
    for (; p + 4 <= e; p += 4) {
      int j0 = __builtin_nontemporal_load(csr + p);
      int j1 = __builtin_nontemporal_load(csr + p + 1);
      int j2 = __builtin_nontemporal_load(csr + p + 2);
      int j3 = __builtin_nontemporal_load(csr + p + 3);
      uint4 u0 = *(const uint4*)(fb + (size_t)j0 * 64 + q * 16);
      uint4 u1 = *(const uint4*)(fb + (size_t)j1 * 64 + q * 16);
      uint4 u2 = *(const uint4*)(fb + (size_t)j2 * 64 + q * 16);
      uint4 u3 = *(const uint4*)(fb + (size_t)j3 * 64 + q * 16);
      float f0[16], f1[16], f2[16], f3[16];
      dec8x16(u0, f0); dec8x16(u1, f1); dec8x16(u2, f2); dec8x16(u3, f3);
#pragma unroll
      for (int i = 0; i < 16; ++i) a[i] += (f0[i] + f1[i]) + (f2[i] + f3[i]);
    }
    for (; p < e; ++p) {
      int j = __builtin_nontemporal_load(csr + p);
      uint4 u = *(const uint4*)(fb + (size_t)j * 64 + q * 16);
      float f[16];
      dec8x16(u, f);
#pragma unroll
      for (int i = 0; i < 16; ++i) a[i] += f[i];
    }
  }
  v8h o0, o1;
#pragma unroll
  for (int i = 0; i < 8; ++i) {
    o0[i] = (_Float16)(a[i] * dinv);
    o1[i] = (_Float16)(a[8 + i] * dinv);
  }
  *(v8h*)(&atile[nd * 72 + q * 16]) = o0;
  *(v8h*)(&atile[nd * 72 + q * 16 + 8]) = o1;
  if (mout && node < n) {
    *(v8h*)(mout + (size_t)node * 64 + q * 16) = o0;
    *(v8h*)(mout + (size_t)node * 64 + q * 16 + 8) = o1;
  }
}

// one 64-row tile of a fused gather+linear stage; t in [0,256)
template <int NSRC, int FUSED>
__device__ __forceinline__ void lin_tile(int t, int tile, const CArgs& A,
    _Float16* atile,
    const _Float16* a0, const _Float16* a1, const _Float16* a2,
    const _Float16* a3, const _Float16* a4, const _Float16* a5,
    int pb0, int pb1, int pb2, int pb3, int pb4, int pb5,
    const unsigned char* gtab, const float* bias,
    _Float16* outp, unsigned char* out8, _Float16* mout, float* colsum) {
  const int lane = t & 63;
  const int wv   = t >> 6;
  const int qd   = lane >> 4;
  const int ln   = lane & 15;
  const int n0   = tile * 64;

  gather_tile(t, n0, gtab, A.offs, A.csr, A.invd, atile, mout, A.n);
  __syncthreads();

  v4f acc[4];
#pragma unroll
  for (int ct = 0; ct < 4; ++ct) acc[ct] = (v4f){0.f, 0.f, 0.f, 0.f};

  const int arow = n0 + wv * 16 + ln;
  const bool arv = arow < A.n;
  const _Float16* srcs[6] = {a0, a1, a2, a3, a4, a5};
  const int pbs[6] = {pb0, pb1, pb2, pb3, pb4, pb5};

#pragma unroll
  for (int s = 0; s < NSRC; ++s) {
    v8h ah0, ah1;
    if (s == FUSED) {
      const _Float16* ph = atile + (wv * 16 + ln) * 72;
      ah0 = *(const v8h*)(ph + qd * 8);
      ah1 = *(const v8h*)(ph + 32 + qd * 8);
    } else if (arv) {
      const _Float16* ph = srcs[s] + (size_t)arow * 64;
      ah0 = *(const v8h*)(ph + qd * 8);
      ah1 = *(const v8h*)(ph + 32 + qd * 8);
    } else {
      v8h z;
#pragma unroll
      for (int j = 0; j < 8; ++j) z[j] = (_Float16)0.f;
      ah0 = ah1 = z;
    }
    const _Float16* pw = A.wpk + (size_t)pbs[s] * PBH;
#pragma unroll
    for (int ct = 0; ct < 4; ++ct) {
      const _Float16* pf0 = pw + (size_t)(ct * 64 + lane) * 8;
      const _Float16* pf1 = pw + (size_t)(512 + ct * 64 + lane) * 8;
      v8h bh0 = *(const v8h*)(pf0);
      v8h bl0v = *(const v8h*)(pf0 + 2048);
      v8h bh1 = *(const v8h*)(pf1);
      v8h bl1v = *(const v8h*)(pf1 + 2048);
      acc[ct] = __builtin_amdgcn_mfma_f32_16x16x32_f16(ah0, bh0, acc[ct], 0, 0, 0);
      acc[ct] = __builtin_amdgcn_mfma_f32_16x16x32_f16(ah0, bl0v, acc[ct], 0, 0, 0);
      acc[ct] = __builtin_amdgcn_mfma_f32_16x16x32_f16(ah1, bh1, acc[ct], 0, 0, 0);
      acc[ct] = __builtin_amdgcn_mfma_f32_16x16x32_f16(ah1, bl1v, acc[ct], 0, 0, 0);
    }
  }

  float bvals[4];
#pragma unroll
  for (int ct = 0; ct < 4; ++ct) bvals[ct] = bias[ct * 16 + ln];

  __syncthreads();   // all atile fragment reads complete; reuse as scratch
  unsigned char* f8t = (unsigned char*)atile;   // 4KB
  float* red = (float*)&atile[2304];             // at byte 4608

  float cs[4] = {0.f, 0.f, 0.f, 0.f};
#pragma unroll
  for (int ct = 0; ct < 4; ++ct) {
#pragma unroll
    for (int r = 0; r < 4; ++r) {
      int nb = wv * 16 + qd * 4 + r;   // C/D: row=(lane>>4)*4+reg, col=lane&15
      int node = n0 + nb;
      float v = fmaxf(acc[ct][r] + bvals[ct], 0.f);   // relu (all lin stages)
      if (node < A.n) {
        if (outp) outp[(size_t)node * 64 + ct * 16 + ln] = (_Float16)v;
        if (out8) f8t[nb * 64 + ct * 16 + ln] = enc8(v);
        cs[ct] += v;
      }
    }
  }
#pragma unroll
  for (int ct = 0; ct < 4; ++ct) {
    float v = cs[ct];
    v += __shfl_xor(v, 16, 64);
    v += __shfl_xor(v, 32, 64);
    if (qd == 0) red[wv * 64 + ct * 16 + ln] = v;
  }
  __syncthreads();
  if (out8) {
    int row = t >> 2, ch = t & 3;
    if (n0 + row < A.n) {
      uint4 val = *(const uint4*)(f8t + row * 64 + ch * 16);
      *(uint4*)(out8 + (size_t)(n0 + row) * 64 + ch * 16) = val;
    }
  }
  if (t < 64) {
    float ssum = red[t] + red[64 + t] + red[128 + t] + red[192 + t];
    atomicAdd(&colsum[t], ssum);
  }
}

// pre-MLP tile (round-8 k_pre body, parameterized); t in [0,256)
__device__ __forceinline__ void pre_tile(int t, int tile, const CArgs& A,
                                         _Float16* atile) {
  const int lane = t & 63;
  const int wv   = t >> 6;
  const int qd   = lane >> 4;
  const int ln   = lane & 15;
  const int n0   = tile * 64;
  const int arow = n0 + wv * 16 + ln;
  const bool arv = arow < A.n;

  v4f acc[4];
#pragma unroll
  for (int ct = 0; ct < 4; ++ct) acc[ct] = (v4f){0.f, 0.f, 0.f, 0.f};
  v8h ah[2];

  auto domfma = [&](int pbi) {
    const _Float16* pw = A.wpk + (size_t)pbi * PBH;
#pragma unroll
    for (int ks = 0; ks < 2; ++ks) {
#pragma unroll
      for (int ct = 0; ct < 4; ++ct) {
        const _Float16* pf = pw + (size_t)(ks * 512 + ct * 64 + lane) * 8;
        v8h bh = *(const v8h*)(pf);
        v8h bl = *(const v8h*)(pf + 2048);
        acc[ct] = __builtin_amdgcn_mfma_f32_16x16x32_f16(ah[ks], bh, acc[ct], 0, 0, 0);
        acc[ct] = __builtin_amdgcn_mfma_f32_16x16x32_f16(ah[ks], bl, acc[ct], 0, 0, 0);
      }
    }
  };

  // stage 1: t0 = relu(nf@W1 + b1); K=128 as two 64-col sources (pb 0,1)
  for (int s = 0; s < 2; ++s) {
#pragma unroll
    for (int ks = 0; ks < 2; ++ks) {
      v8h hv;
      if (arv) {
        const float* p = A.nf + (size_t)arow * 128 + s * 64 + ks * 32 + qd * 8;
        float4 u0 = *(const float4*)(p);
        float4 u1 = *(const float4*)(p + 4);
        hv[0] = (_Float16)u0.x; hv[1] = (_Float16)u0.y;
        hv[2] = (_Float16)u0.z; hv[3] = (_Float16)u0.w;
        hv[4] = (_Float16)u1.x; hv[5] = (_Float16)u1.y;
        hv[6] = (_Float16)u1.z; hv[7] = (_Float16)u1.w;
      } else {
#pragma unroll
        for (int j = 0; j < 8; ++j) hv[j] = (_Float16)0.f;
      }
      ah[ks] = hv;
    }
    domfma(s);
  }

  float b1v[4];
#pragma unroll
  for (int ct = 0; ct < 4; ++ct) b1v[ct] = A.preb1[ct * 16 + ln];
#pragma unroll
  for (int ct = 0; ct < 4; ++ct) {
#pragma unroll
    for (int r = 0; r < 4; ++r) {
      int nb = wv * 16 + qd * 4 + r;
      float v = fmaxf(acc[ct][r] + b1v[ct], 0.f);
      atile[nb * 72 + ct * 16 + ln] = (_Float16)v;
    }
  }
#pragma unroll
  for (int ct = 0; ct < 4; ++ct) acc[ct] = (v4f){0.f, 0.f, 0.f, 0.f};
  __syncthreads();

  // stage 2: x = t0 @ W2 + b2 (pb 2)
  {
    const _Float16* ph = atile + (wv * 16 + ln) * 72;
    ah[0] = *(const v8h*)(ph + qd * 8);
    ah[1] = *(const v8h*)(ph + 32 + qd * 8);
  }
  domfma(2);

  float b2v[4];
#pragma unroll
  for (int ct = 0; ct < 4; ++ct) b2v[ct] = A.preb2[ct * 16 + ln];

  __syncthreads();
  unsigned char* f8t = (unsigned char*)atile;
  float* red = (float*)&atile[2304];
  float cs[4] = {0.f, 0.f, 0.f, 0.f};
#pragma unroll
  for (int ct = 0; ct < 4; ++ct) {
#pragma unroll
    for (int r = 0; r < 4; ++r) {
      int nb = wv * 16 + qd * 4 + r;
      int node = n0 + nb;
      float v = acc[ct][r] + b2v[ct];
      if (node < A.n) {
        A.x[(size_t)node * 64 + ct * 16 + ln] = (_Float16)v;
        f8t[nb * 64 + ct * 16 + ln] = enc8(v);
        cs[ct] += v;
      }
    }
  }
#pragma unroll
  for (int ct = 0; ct < 4; ++ct) {
    float v = cs[ct];
    v += __shfl_xor(v, 16, 64);
    v += __shfl_xor(v, 32, 64);
    if (qd == 0) red[wv * 64 + ct * 16 + ln] = v;
  }
  __syncthreads();
  {
    int row = t >> 2, ch = t & 3;
    if (n0 + row < A.n) {
      uint4 val = *(const uint4*)(f8t + row * 64 + ch * 16);
      *(uint4*)(A.f8a + (size_t)(n0 + row) * 64 + ch * 16) = val;
    }
  }
  if (t < 64) {
    float ssum = red[t] + red[64 + t] + red[128 + t] + red[192 + t];
    atomicAdd(&A.sv[t], ssum);
  }
}

// post-MLP (block 0, all 512 threads reach barriers; work guarded)
__device__ __forceinline__ void post_body(int tt, const CArgs& A, float* Lf) {
  float* sh = Lf; float* h1 = Lf + 256; float* h2 = Lf + 320; float* h3 = Lf + 384;
  if (tt < 256) sh[tt] = A.sv[tt];
  __syncthreads();
  if (tt < 64) {
    float a = A.pb1[tt];
    for (int k = 0; k < 256; ++k) a += sh[k] * A.pw1[k * 64 + tt];
    h1[tt] = (a >= 0.f) ? a : 0.1f * a;
  }
  __syncthreads();
  if (tt < 64) {
    float a = A.pb2[tt];
    for (int k = 0; k < 64; ++k) a += h1[k] * A.pw2[k * 64 + tt];
    h2[tt] = fmaxf(a, 0.f);
  }
  __syncthreads();
  if (tt < 256) {
    float a = A.pb3[tt];
    for (int k = 0; k < 64; ++k) a += h2[k] * A.pw3[k * 256 + tt];
    h3[tt] = fmaxf(a, 0.f);
  }
  __syncthreads();
  if (tt < 64) {
    float a = A.pb4[tt];
    for (int k = 0; k < 256; ++k) a += h3[k] * A.pw4[k * 64 + tt];
    A.outp[tt] = a;
  }
}

__global__ __launch_bounds__(512, 4) void k_compute(CArgs A) {
  cg::grid_group grid = cg::this_grid();
  __shared__ _Float16 atile[2][64 * 72];
  const int t    = threadIdx.x & 255;
  const int hb   = threadIdx.x >> 8;
  const int tile = blockIdx.x * 2 + hb;

  pre_tile(t, tile, A, atile[hb]);
  __threadfence();
  grid.sync();

  lin_tile<2, 0>(t, tile, A, atile[hb],
                 nullptr, A.x, nullptr, nullptr, nullptr, nullptr,
                 3, 4, 0, 0, 0, 0,
                 A.f8a, A.bl0, A.h0, A.f8b, A.m0, A.sv + 64);
  __threadfence();
  grid.sync();

  lin_tile<4, 1>(t, tile, A, atile[hb],
                 A.m0, nullptr, A.x, A.h0, nullptr, nullptr,
                 5, 6, 7, 8, 0, 0,
                 A.f8b, A.bl1, A.h1, A.f8a, A.m1, A.sv + 128);
  __threadfence();
  grid.sync();

  lin_tile<6, 2>(t, tile, A, atile[hb],
                 A.m0, A.m1, nullptr, A.x, A.h0, A.h1,
                 9, 10, 11, 12, 13, 14,
                 A.f8a, A.bl2, nullptr, nullptr, nullptr, A.sv + 192);
  __threadfence();
  grid.sync();

  if (blockIdx.x == 0) post_body(threadIdx.x, A, (float*)&atile[0][0]);
}

// =================== FALLBACK (non-cooperative) kernels =======================
__global__ __launch_bounds__(256) void k_bhist(const int* __restrict__ dst,
                                               int* __restrict__ gbcnt) {
  __shared__ int lcnt[NB];
  int t = threadIdx.x;
  for (int i = t; i < NB; i += 256) lcnt[i] = 0;
  __syncthreads();
  int eb = blockIdx.x * 4096;
#pragma unroll
  for (int i = 0; i < 16; ++i) {
    int e = eb + i * 256 + t;
    if (e < NE) atomicAdd(&lcnt[dst[e] >> 8], 1);
  }
  __syncthreads();
  for (int i = t; i < NB; i += 256)
    if (lcnt[i]) atomicAdd(&gbcnt[i], lcnt[i]);
}

__global__ __launch_bounds__(256) void k_bscan(const int* __restrict__ gbcnt,
                                               int* __restrict__ boff,
                                               int* __restrict__ gcur,
                                               int* __restrict__ offs,
                                               float* __restrict__ sv) {
  __shared__ int sd[256];
  int t = threadIdx.x;
  sv[t] = 0.f;
  int v = (t < NB) ? gbcnt[t] : 0;
  sd[t] = v;
  __syncthreads();
  for (int o = 1; o < 256; o <<= 1) {
    int u = (t >= o) ? sd[t - o] : 0;
    __syncthreads();
    sd[t] += u;
    __syncthreads();
  }
  if (t < NB) { int x = sd[t] - v; boff[t] = x; gcur[t] = x; }
  if (t == NB - 1) boff[NB] = sd[t];
  if (t == 0) offs[NN] = NE;
}

__global__ __launch_bounds__(256) void k_bscatter(const int* __restrict__ src,
                                                  const int* __restrict__ dst,
                                                  int* __restrict__ gcur,
                                                  unsigned* __restrict__ ebuf) {
  __shared__ int cnt[NB];
  __shared__ int base[NB];
  int t = threadIdx.x;
  for (int i = t; i < NB; i += 256) cnt[i] = 0;
  __syncthreads();
  int eb = blockIdx.x * 4096;
  unsigned pk[16];
  int bk[16], lp[16];
#pragma unroll
  for (int i = 0; i < 16; ++i) {
    int e = eb + i * 256 + t;
    if (e < NE) {
      int d = dst[e];
      int b = d >> 8;
      pk[i] = ((unsigned)src[e] << 8) | (unsigned)(d & 255);
      bk[i] = b;
      lp[i] = atomicAdd(&cnt[b], 1);
    }
  }
  __syncthreads();
  for (int i = t; i < NB; i += 256)
    base[i] = cnt[i] ? atomicAdd(&gcur[i], cnt[i]) : 0;
  __syncthreads();
#pragma unroll
  for (int i = 0; i < 16; ++i) {
    int e = eb + i * 256 + t;
    if (e < NE) ebuf[base[bk[i]] + lp[i]] = pk[i];
  }
}

__global__ __launch_bounds__(256) void k_bbuild(const unsigned* __restrict__ ebuf,
                                                const int* __restrict__ boff,
                                                int* __restrict__ offs,
                                                float* __restrict__ invd,
                                                int* __restrict__ csr) {
  __shared__ int dcnt[256];
  __shared__ int cur[256];
  int t = threadIdx.x;
  int b = blockIdx.x;
  int node0 = b << 8;
  int es = boff[b], ee = boff[b + 1];
  dcnt[t] = 0;
  __syncthreads();
  for (int e = es + t; e < ee; e += 256) atomicAdd(&dcnt[ebuf[e] & 255], 1);
  __syncthreads();
  int v = dcnt[t];
  cur[t] = v;
  __syncthreads();
  for (int o = 1; o < 256; o <<= 1) {
    int u = (t >= o) ? cur[t - o] : 0;
    __syncthreads();
    cur[t] += u;
    __syncthreads();
  }
  int excl = cur[t] - v;
  int node = node0 + t;
  if (node < NN) {
    offs[node] = es + excl;
    invd[node] = 1.0f / fmaxf((float)v, 1.0f);
  }
  __syncthreads();
  cur[t] = es + excl;
  __syncthreads();
  for (int e = es + t; e < ee; e += 256) {
    unsigned pk = ebuf[e];
    int p = atomicAdd(&cur[pk & 255], 1);
    csr[p] = (int)(pk >> 8);
  }
}

struct WPackArgs {
  const float* w[15];
  int gidx[15];
  const float* skip;
  _Float16* outp;
};

__global__ __launch_bounds__(256) void k_wpack(WPackArgs A) {
  __shared__ float sw[4096];
  int b = blockIdx.x, t = threadIdx.x;
  const float* w = A.w[b];
#pragma unroll
  for (int i = 0; i < 4; ++i)
    *(float4*)&sw[i * 1024 + t * 4] = *(const float4*)(w + i * 1024 + t * 4);
  float gs = 1.f;
  if (A.gidx[b] >= 0) gs = 1.f / (1.f + __expf(-A.skip[A.gidx[b]]));
  __syncthreads();
#pragma unroll
  for (int i = 0; i < 4; ++i) {
    int u = t * 4 + i;
    int lane = u & 63, ct = (u >> 6) & 3, hl = (u >> 8) & 1, ks = (u >> 9) & 1;
    v8h val;
#pragma unroll
    for (int j = 0; j < 8; ++j) {
      int k = ks * 32 + ((lane >> 4) & 3) * 8 + j;
      int n = ct * 16 + (lane & 15);
      float f = sw[k * 64 + n] * gs;
      _Float16 h = (_Float16)f;
      val[j] = hl ? (_Float16)(f - (float)h) : h;
    }
    *(v8h*)(A.outp + (size_t)b * PBH + (size_t)u * 8) = val;
  }
}

// fallback compute stages reuse CArgs via small wrappers
struct FLinArgs {
  CArgs C;
  const _Float16* a[6];
  int pb[6];
  int nsrc;
  const unsigned char* gtab;
  const float* bias;
  _Float16* outp;
  unsigned char* out8;
  _Float16* mout;
  float* colsum;
};

template <int NSRC, int FUSED>
__global__ __launch_bounds__(256) void k_linF(FLinArgs F) {
  __shared__ _Float16 atile[64 * 72];
  lin_tile<NSRC, FUSED>(threadIdx.x, blockIdx.x, F.C, atile,
                        F.a[0], F.a[1], F.a[2], F.a[3], F.a[4], F.a[5],
                        F.pb[0], F.pb[1], F.pb[2], F.pb[3], F.pb[4], F.pb[5],
                        F.gtab, F.bias, F.outp, F.out8, F.mout, F.colsum);
}

__global__ __launch_bounds__(256) void k_preF(CArgs A) {
  __shared__ _Float16 atile[64 * 72];
  pre_tile(threadIdx.x, blockIdx.x, A, atile);
}

__global__ __launch_bounds__(256) void k_postF(CArgs A) {
  __shared__ float Lf[640];
  post_body(threadIdx.x, A, Lf);
}

// ================================ launcher ====================================
extern "C" void kernel_launch(void* const* d_in, const int* in_sizes, int n_in,
                              void* d_out, int out_size, void* d_ws, size_t ws_size,
                              hipStream_t stream) {
  const float* nf     = (const float*)d_in[0];
  const int*   ei     = (const int*)d_in[1];
  const float* pre_w1 = (const float*)d_in[2];
  const float* pre_b1 = (const float*)d_in[3];
  const float* pre_w2 = (const float*)d_in[4];
  const float* pre_b2 = (const float*)d_in[5];
  const float* skip   = (const float*)d_in[6];
  const float* wl0 = (const float*)d_in[7],  *bl0 = (const float*)d_in[8],  *wr0 = (const float*)d_in[9];
  const float* wl1 = (const float*)d_in[10], *bl1 = (const float*)d_in[11], *wr1 = (const float*)d_in[12];
  const float* wl2 = (const float*)d_in[13], *bl2 = (const float*)d_in[14], *wr2 = (const float*)d_in[15];
  const float* pw1 = (const float*)d_in[16], *pb1 = (const float*)d_in[17];
  const float* pw2 = (const float*)d_in[18], *pb2 = (const float*)d_in[19];
  const float* pw3 = (const float*)d_in[20], *pb3 = (const float*)d_in[21];
  const float* pw4 = (const float*)d_in[22], *pb4 = (const float*)d_in[23];
  float* out = (float*)d_out;

  const int N = NN, E = NE;

  char* ws = (char*)d_ws;
  size_t pos = 0;
  auto alloc = [&](size_t bytes) {
    char* p = ws + pos;
    pos += (bytes + 255) & ~(size_t)255;
    return (void*)p;
  };
  int*      gbcnt = (int*)alloc((size_t)NB * 4);
  int*      boff  = (int*)alloc((size_t)(NB + 1) * 4);
  int*      gcur  = (int*)alloc((size_t)NB * 4);
  unsigned* ebuf  = (unsigned*)alloc((size_t)E * 4);
  int*      offs  = (int*)alloc((size_t)(N + 1) * 4);
  float*    invd  = (float*)alloc((size_t)N * 4);
  int*      csr   = (int*)alloc((size_t)E * 4);
  const size_t PB = (size_t)N * 64 * 2;
  _Float16* x  = (_Float16*)alloc(PB);
  _Float16* h0 = (_Float16*)alloc(PB);
  _Float16* h1 = (_Float16*)alloc(PB);
  _Float16* m0 = (_Float16*)alloc(PB);
  _Float16* m1 = (_Float16*)alloc(PB);
  unsigned char* f8a = (unsigned char*)alloc((size_t)N * 64);
  unsigned char* f8b = (unsigned char*)alloc((size_t)N * 64);
  _Float16* wpk = (_Float16*)alloc((size_t)15 * PBH * 2);
  float* sv = (float*)alloc(256 * 4);

  const int* e_src = ei;
  const int* e_dst = ei + E;
  const float* wsrc[15] = {pre_w1, pre_w1 + 64 * 64, pre_w2,
                           wl0, wr0,
                           wl1, wl1 + 64 * 64, wr1, wr1 + 64 * 64,
                           wl2, wl2 + 64 * 64, wl2 + 128 * 64,
                           wr2, wr2 + 64 * 64, wr2 + 128 * 64};
  const int gi[15] = {-1, -1, -1, 0, 0, 3, 4, 3, 4, 6, 7, 8, 6, 7, 8};

  // ---- cooperative kernel 1: graph build + wpack ----
  GArgs G;
  G.esrc = e_src; G.edst = e_dst;
  G.gbcnt = gbcnt; G.boff = boff; G.gcur = gcur; G.offs = offs;
  G.invd = invd; G.csr = csr; G.ebuf = ebuf; G.sv = sv;
  for (int i = 0; i < 15; ++i) { G.w[i] = wsrc[i]; G.gidx[i] = gi[i]; }
  G.skip = skip; G.wpk = wpk;
  void* gp[] = {(void*)&G};
  hipError_t eg = hipLaunchCooperativeKernel((void*)k_graph, dim3(NB), dim3(256),
                                             gp, 0, stream);
  if (eg != hipSuccess) {
    // fallback: classic 5-dispatch build
    hipMemsetAsync(gbcnt, 0, (size_t)NB * 4, stream);
    WPackArgs W;
    for (int i = 0; i < 15; ++i) { W.w[i] = wsrc[i]; W.gidx[i] = gi[i]; }
    W.skip = skip; W.outp = wpk;
    k_wpack<<<15, 256, 0, stream>>>(W);
    const int EGRID = (E + 4095) / 4096;
    k_bhist<<<EGRID, 256, 0, stream>>>(e_dst, gbcnt);
    k_bscan<<<1, 256, 0, stream>>>(gbcnt, boff, gcur, offs, sv);
    k_bscatter<<<EGRID, 256, 0, stream>>>(e_src, e_dst, gcur, ebuf);
    k_bbuild<<<NB, 256, 0, stream>>>(ebuf, boff, offs, invd, csr);
  }

  // ---- cooperative kernel 2: compute chain ----
  CArgs C;
  C.nf = nf; C.wpk = wpk; C.preb1 = pre_b1; C.preb2 = pre_b2;
  C.bl0 = bl0; C.bl1 = bl1; C.bl2 = bl2;
  C.offs = offs; C.csr = csr; C.invd = invd;
  C.x = x; C.h0 = h0; C.h1 = h1; C.m0 = m0; C.m1 = m1;
  C.f8a = f8a; C.f8b = f8b; C.sv = sv;
  C.pw1 = pw1; C.pb1 = pb1; C.pw2 = pw2; C.pb2 = pb2;
  C.pw3 = pw3; C.pb3 = pb3; C.pw4 = pw4; C.pb4 = pb4;
  C.outp = out; C.n = N;
  void* cp[] = {(void*)&C};
  hipError_t ec = hipLaunchCooperativeKernel((void*)k_compute, dim3(391), dim3(512),
                                             cp, 0, stream);
  if (ec != hipSuccess) {
    // fallback: per-stage dispatches (same math, ping-pong f8)
    const int LGRID = (N + 63) / 64;   // 782
    k_preF<<<LGRID, 256, 0, stream>>>(C);
    {
      FLinArgs F; F.C = C;
      F.a[0] = nullptr; F.a[1] = x; F.a[2] = nullptr; F.a[3] = nullptr;
      F.a[4] = nullptr; F.a[5] = nullptr;
      F.pb[0] = 3; F.pb[1] = 4; F.pb[2] = 0; F.pb[3] = 0; F.pb[4] = 0; F.pb[5] = 0;
      F.nsrc = 2; F.gtab = f8a; F.bias = bl0;
      F.outp = h0; F.out8 = f8b; F.mout = m0; F.colsum = sv + 64;
      k_linF<2, 0><<<LGRID, 256, 0, stream>>>(F);
    }
    {
      FLinArgs F; F.C = C;
      F.a[0] = m0; F.a[1] = nullptr; F.a[2] = x; F.a[3] = h0;
      F.a[4] = nullptr; F.a[5] = nullptr;
      F.pb[0] = 5; F.pb[1] = 6; F.pb[2] = 7; F.pb[3] = 8; F.pb[4] = 0; F.pb[5] = 0;
      F.nsrc = 4; F.gtab = f8b; F.bias = bl1;
      F.outp = h1; F.out8 = f8a; F.mout = m1; F.colsum = sv + 128;
      k_linF<4, 1><<<LGRID, 256, 0, stream>>>(F);
    }
    {
      FLinArgs F; F.C = C;
      F.a[0] = m0; F.a[1] = m1; F.a[2] = nullptr; F.a[3] = x;
      F.a[4] = h0; F.a[5] = h1;
      F.pb[0] = 9; F.pb[1] = 10; F.pb[2] = 11; F.pb[3] = 12; F.pb[4] = 13; F.pb[5] = 14;
      F.nsrc = 6; F.gtab = f8a; F.bias = bl2;
      F.outp = nullptr; F.out8 = nullptr; F.mout = nullptr; F.colsum = sv + 192;
      k_linF<6, 2><<<LGRID, 256, 0, stream>>>(F);
    }
    k_postF<<<1, 256, 0, stream>>>(C);
  }
}

// Round 10
// 333.854 us; speedup vs baseline: 2.5336x; 2.5336x over previous
//
#include <hip/hip_runtime.h>
#include <math.h>

#define NN 50000
#define NE 800000
#define NB 196        // dst buckets of 256 nodes
#define SLOT 8192     // fixed edge capacity per bucket (mean 4081, max ~4400)
#define PBH 8192      // halfs per packed 64x64 W block: 2ks*2hl*4ct*64lane*8

typedef float v4f __attribute__((ext_vector_type(4)));
typedef float v2f __attribute__((ext_vector_type(2)));
typedef _Float16 v8h __attribute__((ext_vector_type(8)));

// ---------------- fp8 e4m3fn helpers: HW builtins w/ fallback ----------------
__device__ __forceinline__ unsigned char enc8(float v) {
#if __has_builtin(__builtin_amdgcn_cvt_pk_fp8_f32)
  return (unsigned char)(__builtin_amdgcn_cvt_pk_fp8_f32(v, v, 0, false) & 0xFF);
#else
  unsigned u = __float_as_uint(v);
  unsigned s = (u >> 24) & 0x80u;
  unsigned au = u & 0x7fffffffu;
  float a = __uint_as_float(au);
  if (au < 0x3C800000u) {
    int m = (int)(a * 512.0f + 0.5f);
    if (m >= 8) return (unsigned char)(s | 8u);
    return (unsigned char)(s | (unsigned)m);
  }
  unsigned r = au + 0x7FFFFu + ((au >> 20) & 1u);
  unsigned e = (r >> 23) - 120u;
  unsigned man = (r >> 20) & 7u;
  if (e > 15u) { e = 15u; man = 6u; }
  return (unsigned char)(s | (e << 3) | man);
#endif
}

#if __has_builtin(__builtin_amdgcn_cvt_pk_f32_fp8)
#define DEC8_HW 1
#else
__device__ __forceinline__ float dec8_1(unsigned b) {
  unsigned s = (b & 0x80u) << 24;
  unsigned em = b & 0x7fu;
  float v;
  if (em >= 8u) v = __uint_as_float((((em >> 3) + 120u) << 23) | ((em & 7u) << 20));
  else v = (float)em * 0.001953125f;
  return __uint_as_float(__float_as_uint(v) | s);
}
#endif

__device__ __forceinline__ void dec8x8(uint2 u, float* f) {
#ifdef DEC8_HW
  v2f p0 = __builtin_amdgcn_cvt_pk_f32_fp8((int)u.x, false);
  v2f p1 = __builtin_amdgcn_cvt_pk_f32_fp8((int)u.x, true);
  v2f p2 = __builtin_amdgcn_cvt_pk_f32_fp8((int)u.y, false);
  v2f p3 = __builtin_amdgcn_cvt_pk_f32_fp8((int)u.y, true);
  f[0] = p0.x; f[1] = p0.y; f[2] = p1.x; f[3] = p1.y;
  f[4] = p2.x; f[5] = p2.y; f[6] = p3.x; f[7] = p3.y;
#else
#pragma unroll
  for (int i = 0; i < 4; ++i) f[i] = dec8_1((u.x >> (8 * i)) & 0xFF);
#pragma unroll
  for (int i = 0; i < 4; ++i) f[4 + i] = dec8_1((u.y >> (8 * i)) & 0xFF);
#endif
}
__device__ __forceinline__ void dec8x16(uint4 u, float* f) {
  dec8x8(make_uint2(u.x, u.y), f);
  dec8x8(make_uint2(u.z, u.w), f + 8);
}

// ============ weight pre-pack + zero-init (block 15) ==========================
struct WPackArgs {
  const float* w[15];
  int gidx[15];
  const float* skip;
  _Float16* outp;
  int* gcur;     // [NB] zeroed by block 15
  float* sv;     // [256] zeroed by block 15
  int* done;     // [1]  zeroed by block 15
};

__global__ __launch_bounds__(256) void k_wpack(WPackArgs A) {
  __shared__ float sw[4096];
  int b = blockIdx.x, t = threadIdx.x;
  if (b == 15) {
    if (t < NB) A.gcur[t] = 0;
    A.sv[t] = 0.f;
    if (t == 0) *A.done = 0;
    return;
  }
  const float* w = A.w[b];
#pragma unroll
  for (int i = 0; i < 4; ++i)
    *(float4*)&sw[i * 1024 + t * 4] = *(const float4*)(w + i * 1024 + t * 4);
  float gs = 1.f;
  if (A.gidx[b] >= 0) gs = 1.f / (1.f + __expf(-A.skip[A.gidx[b]]));
  __syncthreads();
#pragma unroll
  for (int i = 0; i < 4; ++i) {
    int u = t * 4 + i;   // u = ks*512 + hl*256 + ct*64 + lane
    int lane = u & 63, ct = (u >> 6) & 3, hl = (u >> 8) & 1, ks = (u >> 9) & 1;
    v8h val;
#pragma unroll
    for (int j = 0; j < 8; ++j) {
      int k = ks * 32 + ((lane >> 4) & 3) * 8 + j;
      int n = ct * 16 + (lane & 15);
      float f = sw[k * 64 + n] * gs;
      _Float16 h = (_Float16)f;
      val[j] = hl ? (_Float16)(f - (float)h) : h;
    }
    *(v8h*)(A.outp + (size_t)b * PBH + (size_t)u * 8) = val;
  }
}

// ============ graph build: fixed-slot scatter (no hist/scan) ==================
__global__ __launch_bounds__(256) void k_bscatter2(const int* __restrict__ src,
                                                   const int* __restrict__ dst,
                                                   int* __restrict__ gcur,
                                                   unsigned* __restrict__ ebuf) {
  __shared__ int cnt[NB];
  __shared__ int base[NB];
  int t = threadIdx.x;
  for (int i = t; i < NB; i += 256) cnt[i] = 0;
  __syncthreads();
  int eb = blockIdx.x * 4096;
  unsigned pk[16];
  int bk[16], lp[16];
#pragma unroll
  for (int i = 0; i < 16; ++i) {
    int e = eb + i * 256 + t;
    if (e < NE) {
      int d = dst[e];
      int b = d >> 8;
      pk[i] = ((unsigned)src[e] << 8) | (unsigned)(d & 255);
      bk[i] = b;
      lp[i] = atomicAdd(&cnt[b], 1);
    }
  }
  __syncthreads();
  for (int i = t; i < NB; i += 256)
    base[i] = cnt[i] ? (i * SLOT + atomicAdd(&gcur[i], cnt[i])) : 0;
  __syncthreads();
#pragma unroll
  for (int i = 0; i < 16; ++i) {
    int e = eb + i * 256 + t;
    if (e < NE) {
      int p = base[bk[i]] + lp[i];
      if (p < (bk[i] + 1) * SLOT) ebuf[p] = pk[i];   // overflow guard
    }
  }
}

// per-bucket degree + scan + csr scatter; writes offs/ends (slotted csr)
__global__ __launch_bounds__(256) void k_bbuild2(const unsigned* __restrict__ ebuf,
                                                 const int* __restrict__ gcur,
                                                 int* __restrict__ offs,
                                                 int* __restrict__ ends,
                                                 float* __restrict__ invd,
                                                 int* __restrict__ csr) {
  __shared__ int dcnt[256];
  __shared__ int cur[256];
  int t = threadIdx.x;
  int b = blockIdx.x;
  int node0 = b << 8;
  int es = b * SLOT;
  int ee = es + min(gcur[b], SLOT);
  dcnt[t] = 0;
  __syncthreads();
  for (int e = es + t; e < ee; e += 256) atomicAdd(&dcnt[ebuf[e] & 255], 1);
  __syncthreads();
  int v = dcnt[t];
  cur[t] = v;
  __syncthreads();
  for (int o = 1; o < 256; o <<= 1) {
    int u = (t >= o) ? cur[t - o] : 0;
    __syncthreads();
    cur[t] += u;
    __syncthreads();
  }
  int excl = cur[t] - v;
  int node = node0 + t;
  if (node < NN) {
    offs[node] = es + excl;
    ends[node] = es + excl + v;
    invd[node] = 1.0f / fmaxf((float)v, 1.0f);
  }
  __syncthreads();
  cur[t] = es + excl;
  __syncthreads();
  for (int e = es + t; e < ee; e += 256) {
    unsigned pk = ebuf[e];
    int p = atomicAdd(&cur[pk & 255], 1);
    csr[p] = (int)(pk >> 8);
  }
}

// =================== compute-stage shared device code =========================
struct CArgs {
  const float* nf; const _Float16* wpk;
  const float* preb1; const float* preb2;
  const float* bl0; const float* bl1; const float* bl2;
  const int* offs; const int* ends; const int* csr; const float* invd;
  _Float16 *x, *h0, *h1, *m0, *m1;
  unsigned char *f8a, *f8b;
  float* sv;
  int* done;
  const float *pw1, *pb1, *pw2, *pb2, *pw3, *pb3, *pw4, *pb4;
  float* outp;
  int n;
};

// gather/mean: 4 thr/node over 256-thread block (measured round-4 body)
__device__ __forceinline__ void gather_tile(int t, int n0,
    const unsigned char* __restrict__ fb, const int* __restrict__ offs,
    const int* __restrict__ ends, const int* __restrict__ csr,
    const float* __restrict__ invd,
    _Float16* atile, _Float16* mout, int n) {
  const int nd = t >> 2, q = t & 3;
  const int node = n0 + nd;
  float a[16];
#pragma unroll
  for (int i = 0; i < 16; ++i) a[i] = 0.f;
  float dinv = 0.f;
  if (node < n) {
    int s = offs[node], e = ends[node];
    dinv = invd[node];
    int p = s;
    for (; p + 4 <= e; p += 4) {
      int j0 = __builtin_nontemporal_load(csr + p);
      int j1 = __builtin_nontemporal_load(csr + p + 1);
      int j2 = __builtin_nontemporal_load(csr + p + 2);
      int j3 = __builtin_nontemporal_load(csr + p + 3);
      uint4 u0 = *(const uint4*)(fb + (size_t)j0 * 64 + q * 16);
      uint4 u1 = *(const uint4*)(fb + (size_t)j1 * 64 + q * 16);
      uint4 u2 = *(const uint4*)(fb + (size_t)j2 * 64 + q * 16);
      uint4 u3 = *(const uint4*)(fb + (size_t)j3 * 64 + q * 16);
      float f0[16], f1[16], f2[16], f3[16];
      dec8x16(u0, f0); dec8x16(u1, f1); dec8x16(u2, f2); dec8x16(u3, f3);
#pragma unroll
      for (int i = 0; i < 16; ++i) a[i] += (f0[i] + f1[i]) + (f2[i] + f3[i]);
    }
    for (; p < e; ++p) {
      int j = __builtin_nontemporal_load(csr + p);
      uint4 u = *(const uint4*)(fb + (size_t)j * 64 + q * 16);
      float f[16];
      dec8x16(u, f);
#pragma unroll
      for (int i = 0; i < 16; ++i) a[i] += f[i];
    }
  }
  v8h o0, o1;
#pragma unroll
  for (int i = 0; i < 8; ++i) {
    o0[i] = (_Float16)(a[i] * dinv);
    o1[i] = (_Float16)(a[8 + i] * dinv);
  }
  *(v8h*)(&atile[nd * 72 + q * 16]) = o0;
  *(v8h*)(&atile[nd * 72 + q * 16 + 8]) = o1;
  if (mout && node < n) {
    *(v8h*)(mout + (size_t)node * 64 + q * 16) = o0;
    *(v8h*)(mout + (size_t)node * 64 + q * 16 + 8) = o1;
  }
}

// one 64-row tile of a fused gather+linear stage; t in [0,256)
template <int NSRC, int FUSED>
__device__ __forceinline__ void lin_tile(int t, int tile, const CArgs& A,
    _Float16* atile,
    const _Float16* a0, const _Float16* a1, const _Float16* a2,
    const _Float16* a3, const _Float16* a4, const _Float16* a5,
    int pb0, int pb1, int pb2, int pb3, int pb4, int pb5,
    const unsigned char* gtab, const float* bias,
    _Float16* outp, unsigned char* out8, _Float16* mout, float* colsum) {
  const int lane = t & 63;
  const int wv   = t >> 6;
  const int qd   = lane >> 4;
  const int ln   = lane & 15;
  const int n0   = tile * 64;

  gather_tile(t, n0, gtab, A.offs, A.ends, A.csr, A.invd, atile, mout, A.n);
  __syncthreads();

  v4f acc[4];
#pragma unroll
  for (int ct = 0; ct < 4; ++ct) acc[ct] = (v4f){0.f, 0.f, 0.f, 0.f};

  const int arow = n0 + wv * 16 + ln;
  const bool arv = arow < A.n;
  const _Float16* srcs[6] = {a0, a1, a2, a3, a4, a5};
  const int pbs[6] = {pb0, pb1, pb2, pb3, pb4, pb5};

#pragma unroll
  for (int s = 0; s < NSRC; ++s) {
    v8h ah0, ah1;
    if (s == FUSED) {
      const _Float16* ph = atile + (wv * 16 + ln) * 72;
      ah0 = *(const v8h*)(ph + qd * 8);
      ah1 = *(const v8h*)(ph + 32 + qd * 8);
    } else if (arv) {
      const _Float16* ph = srcs[s] + (size_t)arow * 64;
      ah0 = *(const v8h*)(ph + qd * 8);
      ah1 = *(const v8h*)(ph + 32 + qd * 8);
    } else {
      v8h z;
#pragma unroll
      for (int j = 0; j < 8; ++j) z[j] = (_Float16)0.f;
      ah0 = ah1 = z;
    }
    const _Float16* pw = A.wpk + (size_t)pbs[s] * PBH;
#pragma unroll
    for (int ct = 0; ct < 4; ++ct) {
      const _Float16* pf0 = pw + (size_t)(ct * 64 + lane) * 8;
      const _Float16* pf1 = pw + (size_t)(512 + ct * 64 + lane) * 8;
      v8h bh0 = *(const v8h*)(pf0);
      v8h bl0v = *(const v8h*)(pf0 + 2048);
      v8h bh1 = *(const v8h*)(pf1);
      v8h bl1v = *(const v8h*)(pf1 + 2048);
      acc[ct] = __builtin_amdgcn_mfma_f32_16x16x32_f16(ah0, bh0, acc[ct], 0, 0, 0);
      acc[ct] = __builtin_amdgcn_mfma_f32_16x16x32_f16(ah0, bl0v, acc[ct], 0, 0, 0);
      acc[ct] = __builtin_amdgcn_mfma_f32_16x16x32_f16(ah1, bh1, acc[ct], 0, 0, 0);
      acc[ct] = __builtin_amdgcn_mfma_f32_16x16x32_f16(ah1, bl1v, acc[ct], 0, 0, 0);
    }
  }

  float bvals[4];
#pragma unroll
  for (int ct = 0; ct < 4; ++ct) bvals[ct] = bias[ct * 16 + ln];

  __syncthreads();   // all atile fragment reads complete; reuse as scratch
  unsigned char* f8t = (unsigned char*)atile;   // 4KB
  float* red = (float*)&atile[2304];             // at byte 4608

  float cs[4] = {0.f, 0.f, 0.f, 0.f};
#pragma unroll
  for (int ct = 0; ct < 4; ++ct) {
#pragma unroll
    for (int r = 0; r < 4; ++r) {
      int nb = wv * 16 + qd * 4 + r;   // C/D: row=(lane>>4)*4+reg, col=lane&15
      int node = n0 + nb;
      float v = fmaxf(acc[ct][r] + bvals[ct], 0.f);   // relu (all lin stages)
      if (node < A.n) {
        if (outp) outp[(size_t)node * 64 + ct * 16 + ln] = (_Float16)v;
        if (out8) f8t[nb * 64 + ct * 16 + ln] = enc8(v);
        cs[ct] += v;
      }
    }
  }
#pragma unroll
  for (int ct = 0; ct < 4; ++ct) {
    float v = cs[ct];
    v += __shfl_xor(v, 16, 64);
    v += __shfl_xor(v, 32, 64);
    if (qd == 0) red[wv * 64 + ct * 16 + ln] = v;
  }
  __syncthreads();
  if (out8) {
    int row = t >> 2, ch = t & 3;
    if (n0 + row < A.n) {
      uint4 val = *(const uint4*)(f8t + row * 64 + ch * 16);
      *(uint4*)(out8 + (size_t)(n0 + row) * 64 + ch * 16) = val;
    }
  }
  if (t < 64) {
    float ssum = red[t] + red[64 + t] + red[128 + t] + red[192 + t];
    atomicAdd(&colsum[t], ssum);
  }
}

// pre-MLP tile (verified round-8/9 body); t in [0,256)
__device__ __forceinline__ void pre_tile(int t, int tile, const CArgs& A,
                                         _Float16* atile) {
  const int lane = t & 63;
  const int wv   = t >> 6;
  const int qd   = lane >> 4;
  const int ln   = lane & 15;
  const int n0   = tile * 64;
  const int arow = n0 + wv * 16 + ln;
  const bool arv = arow < A.n;

  v4f acc[4];
#pragma unroll
  for (int ct = 0; ct < 4; ++ct) acc[ct] = (v4f){0.f, 0.f, 0.f, 0.f};
  v8h ah[2];

  auto domfma = [&](int pbi) {
    const _Float16* pw = A.wpk + (size_t)pbi * PBH;
#pragma unroll
    for (int ks = 0; ks < 2; ++ks) {
#pragma unroll
      for (int ct = 0; ct < 4; ++ct) {
        const _Float16* pf = pw + (size_t)(ks * 512 + ct * 64 + lane) * 8;
        v8h bh = *(const v8h*)(pf);
        v8h bl = *(const v8h*)(pf + 2048);
        acc[ct] = __builtin_amdgcn_mfma_f32_16x16x32_f16(ah[ks], bh, acc[ct], 0, 0, 0);
        acc[ct] = __builtin_amdgcn_mfma_f32_16x16x32_f16(ah[ks], bl, acc[ct], 0, 0, 0);
      }
    }
  };

  // stage 1: t0 = relu(nf@W1 + b1); K=128 as two 64-col sources (pb 0,1)
  for (int s = 0; s < 2; ++s) {
#pragma unroll
    for (int ks = 0; ks < 2; ++ks) {
      v8h hv;
      if (arv) {
        const float* p = A.nf + (size_t)arow * 128 + s * 64 + ks * 32 + qd * 8;
        float4 u0 = *(const float4*)(p);
        float4 u1 = *(const float4*)(p + 4);
        hv[0] = (_Float16)u0.x; hv[1] = (_Float16)u0.y;
        hv[2] = (_Float16)u0.z; hv[3] = (_Float16)u0.w;
        hv[4] = (_Float16)u1.x; hv[5] = (_Float16)u1.y;
        hv[6] = (_Float16)u1.z; hv[7] = (_Float16)u1.w;
      } else {
#pragma unroll
        for (int j = 0; j < 8; ++j) hv[j] = (_Float16)0.f;
      }
      ah[ks] = hv;
    }
    domfma(s);
  }

  float b1v[4];
#pragma unroll
  for (int ct = 0; ct < 4; ++ct) b1v[ct] = A.preb1[ct * 16 + ln];
#pragma unroll
  for (int ct = 0; ct < 4; ++ct) {
#pragma unroll
    for (int r = 0; r < 4; ++r) {
      int nb = wv * 16 + qd * 4 + r;
      float v = fmaxf(acc[ct][r] + b1v[ct], 0.f);
      atile[nb * 72 + ct * 16 + ln] = (_Float16)v;
    }
  }
#pragma unroll
  for (int ct = 0; ct < 4; ++ct) acc[ct] = (v4f){0.f, 0.f, 0.f, 0.f};
  __syncthreads();

  // stage 2: x = t0 @ W2 + b2 (pb 2)
  {
    const _Float16* ph = atile + (wv * 16 + ln) * 72;
    ah[0] = *(const v8h*)(ph + qd * 8);
    ah[1] = *(const v8h*)(ph + 32 + qd * 8);
  }
  domfma(2);

  float b2v[4];
#pragma unroll
  for (int ct = 0; ct < 4; ++ct) b2v[ct] = A.preb2[ct * 16 + ln];

  __syncthreads();
  unsigned char* f8t = (unsigned char*)atile;
  float* red = (float*)&atile[2304];
  float cs[4] = {0.f, 0.f, 0.f, 0.f};
#pragma unroll
  for (int ct = 0; ct < 4; ++ct) {
#pragma unroll
    for (int r = 0; r < 4; ++r) {
      int nb = wv * 16 + qd * 4 + r;
      int node = n0 + nb;
      float v = acc[ct][r] + b2v[ct];
      if (node < A.n) {
        A.x[(size_t)node * 64 + ct * 16 + ln] = (_Float16)v;
        f8t[nb * 64 + ct * 16 + ln] = enc8(v);
        cs[ct] += v;
      }
    }
  }
#pragma unroll
  for (int ct = 0; ct < 4; ++ct) {
    float v = cs[ct];
    v += __shfl_xor(v, 16, 64);
    v += __shfl_xor(v, 32, 64);
    if (qd == 0) red[wv * 64 + ct * 16 + ln] = v;
  }
  __syncthreads();
  {
    int row = t >> 2, ch = t & 3;
    if (n0 + row < A.n) {
      uint4 val = *(const uint4*)(f8t + row * 64 + ch * 16);
      *(uint4*)(A.f8a + (size_t)(n0 + row) * 64 + ch * 16) = val;
    }
  }
  if (t < 64) {
    float ssum = red[t] + red[64 + t] + red[128 + t] + red[192 + t];
    atomicAdd(&A.sv[t], ssum);
  }
}

// post-MLP; sv read via device-scope atomics (cross-XCD safe in last block)
__device__ __forceinline__ void post_body(int tt, const CArgs& A, float* Lf) {
  float* sh = Lf; float* h1 = Lf + 256; float* h2 = Lf + 320; float* h3 = Lf + 384;
  if (tt < 256) sh[tt] = atomicAdd(&A.sv[tt], 0.0f);
  __syncthreads();
  if (tt < 64) {
    float a = A.pb1[tt];
    for (int k = 0; k < 256; ++k) a += sh[k] * A.pw1[k * 64 + tt];
    h1[tt] = (a >= 0.f) ? a : 0.1f * a;
  }
  __syncthreads();
  if (tt < 64) {
    float a = A.pb2[tt];
    for (int k = 0; k < 64; ++k) a += h1[k] * A.pw2[k * 64 + tt];
    h2[tt] = fmaxf(a, 0.f);
  }
  __syncthreads();
  if (tt < 256) {
    float a = A.pb3[tt];
    for (int k = 0; k < 64; ++k) a += h2[k] * A.pw3[k * 256 + tt];
    h3[tt] = fmaxf(a, 0.f);
  }
  __syncthreads();
  if (tt < 64) {
    float a = A.pb4[tt];
    for (int k = 0; k < 256; ++k) a += h3[k] * A.pw4[k * 64 + tt];
    A.outp[tt] = a;
  }
}

// =================== stage kernels ===========================================
__global__ __launch_bounds__(256) void k_preF(CArgs A) {
  __shared__ _Float16 atile[64 * 72];
  pre_tile(threadIdx.x, blockIdx.x, A, atile);
}

struct FLinArgs {
  CArgs C;
  const _Float16* a[6];
  int pb[6];
  const unsigned char* gtab;
  const float* bias;
  _Float16* outp;
  unsigned char* out8;
  _Float16* mout;
  float* colsum;
};

template <int NSRC, int FUSED, int DOPOST>
__global__ __launch_bounds__(256) void k_linF(FLinArgs F) {
  __shared__ _Float16 atile[64 * 72];
  __shared__ int lastflag;
  lin_tile<NSRC, FUSED>(threadIdx.x, blockIdx.x, F.C, atile,
                        F.a[0], F.a[1], F.a[2], F.a[3], F.a[4], F.a[5],
                        F.pb[0], F.pb[1], F.pb[2], F.pb[3], F.pb[4], F.pb[5],
                        F.gtab, F.bias, F.outp, F.out8, F.mout, F.colsum);
  if (DOPOST) {
    __syncthreads();
    __threadfence();
    if (threadIdx.x == 0)
      lastflag = (atomicAdd(F.C.done, 1) == (int)gridDim.x - 1);
    __syncthreads();
    if (lastflag) post_body(threadIdx.x, F.C, (float*)atile);
  }
}

// ================================ launcher ====================================
extern "C" void kernel_launch(void* const* d_in, const int* in_sizes, int n_in,
                              void* d_out, int out_size, void* d_ws, size_t ws_size,
                              hipStream_t stream) {
  const float* nf     = (const float*)d_in[0];
  const int*   ei     = (const int*)d_in[1];
  const float* pre_w1 = (const float*)d_in[2];
  const float* pre_b1 = (const float*)d_in[3];
  const float* pre_w2 = (const float*)d_in[4];
  const float* pre_b2 = (const float*)d_in[5];
  const float* skip   = (const float*)d_in[6];
  const float* wl0 = (const float*)d_in[7],  *bl0 = (const float*)d_in[8],  *wr0 = (const float*)d_in[9];
  const float* wl1 = (const float*)d_in[10], *bl1 = (const float*)d_in[11], *wr1 = (const float*)d_in[12];
  const float* wl2 = (const float*)d_in[13], *bl2 = (const float*)d_in[14], *wr2 = (const float*)d_in[15];
  const float* pw1 = (const float*)d_in[16], *pb1 = (const float*)d_in[17];
  const float* pw2 = (const float*)d_in[18], *pb2 = (const float*)d_in[19];
  const float* pw3 = (const float*)d_in[20], *pb3 = (const float*)d_in[21];
  const float* pw4 = (const float*)d_in[22], *pb4 = (const float*)d_in[23];
  float* out = (float*)d_out;

  const int N = NN, E = NE;

  char* ws = (char*)d_ws;
  size_t pos = 0;
  auto alloc = [&](size_t bytes) {
    char* p = ws + pos;
    pos += (bytes + 255) & ~(size_t)255;
    return (void*)p;
  };
  int*      gcur  = (int*)alloc((size_t)NB * 4);
  unsigned* ebuf  = (unsigned*)alloc((size_t)NB * SLOT * 4);
  int*      offs  = (int*)alloc((size_t)N * 4);
  int*      ends  = (int*)alloc((size_t)N * 4);
  float*    invd  = (float*)alloc((size_t)N * 4);
  int*      csr   = (int*)alloc((size_t)NB * SLOT * 4);
  const size_t PB = (size_t)N * 64 * 2;
  _Float16* x  = (_Float16*)alloc(PB);
  _Float16* h0 = (_Float16*)alloc(PB);
  _Float16* h1 = (_Float16*)alloc(PB);
  _Float16* m0 = (_Float16*)alloc(PB);
  _Float16* m1 = (_Float16*)alloc(PB);
  unsigned char* f8a = (unsigned char*)alloc((size_t)N * 64);
  unsigned char* f8b = (unsigned char*)alloc((size_t)N * 64);
  _Float16* wpk = (_Float16*)alloc((size_t)15 * PBH * 2);
  float* sv = (float*)alloc(256 * 4);
  int* done = (int*)alloc(256);

  const int* e_src = ei;
  const int* e_dst = ei + E;
  const float* wsrc[15] = {pre_w1, pre_w1 + 64 * 64, pre_w2,
                           wl0, wr0,
                           wl1, wl1 + 64 * 64, wr1, wr1 + 64 * 64,
                           wl2, wl2 + 64 * 64, wl2 + 128 * 64,
                           wr2, wr2 + 64 * 64, wr2 + 128 * 64};
  const int gi[15] = {-1, -1, -1, 0, 0, 3, 4, 3, 4, 6, 7, 8, 6, 7, 8};

  // 1) weight pre-pack + zero-init (block 15)
  {
    WPackArgs W;
    for (int i = 0; i < 15; ++i) { W.w[i] = wsrc[i]; W.gidx[i] = gi[i]; }
    W.skip = skip; W.outp = wpk;
    W.gcur = gcur; W.sv = sv; W.done = done;
    k_wpack<<<16, 256, 0, stream>>>(W);
  }

  // 2) fixed-slot edge scatter, 3) per-bucket csr build
  const int EGRID = (E + 4095) / 4096;   // 196
  k_bscatter2<<<EGRID, 256, 0, stream>>>(e_src, e_dst, gcur, ebuf);
  k_bbuild2<<<NB, 256, 0, stream>>>(ebuf, gcur, offs, ends, invd, csr);

  CArgs C;
  C.nf = nf; C.wpk = wpk; C.preb1 = pre_b1; C.preb2 = pre_b2;
  C.bl0 = bl0; C.bl1 = bl1; C.bl2 = bl2;
  C.offs = offs; C.ends = ends; C.csr = csr; C.invd = invd;
  C.x = x; C.h0 = h0; C.h1 = h1; C.m0 = m0; C.m1 = m1;
  C.f8a = f8a; C.f8b = f8b; C.sv = sv; C.done = done;
  C.pw1 = pw1; C.pb1 = pb1; C.pw2 = pw2; C.pb2 = pb2;
  C.pw3 = pw3; C.pb3 = pb3; C.pw4 = pw4; C.pb4 = pb4;
  C.outp = out; C.n = N;

  const int LGRID = (N + 63) / 64;   // 782

  // 4) fused pre-MLP: x (fp16) + f8a + colsum sv[0:64]
  k_preF<<<LGRID, 256, 0, stream>>>(C);

  // 5) layer 0: gather f8a -> m0; h0 = relu(m0@wl0 + x@wr0 + bl0); writes f8b
  {
    FLinArgs F; F.C = C;
    F.a[0] = nullptr; F.a[1] = x; F.a[2] = nullptr; F.a[3] = nullptr;
    F.a[4] = nullptr; F.a[5] = nullptr;
    F.pb[0] = 3; F.pb[1] = 4; F.pb[2] = 0; F.pb[3] = 0; F.pb[4] = 0; F.pb[5] = 0;
    F.gtab = f8a; F.bias = bl0;
    F.outp = h0; F.out8 = f8b; F.mout = m0; F.colsum = sv + 64;
    k_linF<2, 0, 0><<<LGRID, 256, 0, stream>>>(F);
  }

  // 6) layer 1: gather f8b -> m1; sources m0,(m1),x,h0; writes f8a
  {
    FLinArgs F; F.C = C;
    F.a[0] = m0; F.a[1] = nullptr; F.a[2] = x; F.a[3] = h0;
    F.a[4] = nullptr; F.a[5] = nullptr;
    F.pb[0] = 5; F.pb[1] = 6; F.pb[2] = 7; F.pb[3] = 8; F.pb[4] = 0; F.pb[5] = 0;
    F.gtab = f8b; F.bias = bl1;
    F.outp = h1; F.out8 = f8a; F.mout = m1; F.colsum = sv + 128;
    k_linF<4, 1, 0><<<LGRID, 256, 0, stream>>>(F);
  }

  // 7) layer 2: gather f8a -> (m2); colsum only; last block runs post-MLP
  {
    FLinArgs F; F.C = C;
    F.a[0] = m0; F.a[1] = m1; F.a[2] = nullptr; F.a[3] = x;
    F.a[4] = h0; F.a[5] = h1;
    F.pb[0] = 9; F.pb[1] = 10; F.pb[2] = 11; F.pb[3] = 12; F.pb[4] = 13; F.pb[5] = 14;
    F.gtab = f8a; F.bias = bl2;
    F.outp = nullptr; F.out8 = nullptr; F.mout = nullptr; F.colsum = sv + 192;
    k_linF<6, 2, 1><<<LGRID, 256, 0, stream>>>(F);
  }
}